// Round 1
// baseline (918.550 us; speedup 1.0000x reference)
//
#include <hip/hip_runtime.h>

static inline int ceil_div(int a, int b) { return (a + b - 1) / b; }

// ---------------- graph preprocessing ----------------

__global__ void k_init_cnt(int* __restrict__ cnt, int N) {
    int i = blockIdx.x * blockDim.x + threadIdx.x;
    if (i < N) cnt[i] = 1;  // self-loop
}

__global__ void k_count(const int* __restrict__ dst, int E, int* __restrict__ cnt) {
    int e = blockIdx.x * blockDim.x + threadIdx.x;
    if (e < E) atomicAdd(&cnt[dst[e]], 1);
}

// single-block exclusive scan of cnt -> row_ptr (and cursor copy), plus dinv = rsqrt(deg)
__global__ __launch_bounds__(256) void k_scan(const int* __restrict__ cnt, int* __restrict__ row_ptr,
                                              int* __restrict__ cursor, float* __restrict__ dinv, int N) {
    __shared__ int sm[256];
    int tid = threadIdx.x;
    int chunk = (N + 255) >> 8;
    int begin = tid * chunk;
    int end = min(begin + chunk, N);
    int s = 0;
    for (int i = begin; i < end; ++i) s += cnt[i];
    sm[tid] = s;
    __syncthreads();
    for (int off = 1; off < 256; off <<= 1) {
        int v = (tid >= off) ? sm[tid - off] : 0;
        __syncthreads();
        sm[tid] += v;
        __syncthreads();
    }
    int run = sm[tid] - s;  // exclusive prefix
    for (int i = begin; i < end; ++i) {
        int c = cnt[i];
        row_ptr[i] = run;
        cursor[i] = run;
        dinv[i] = rsqrtf((float)c);
        run += c;
    }
    if (tid == 255) row_ptr[N] = sm[255];
}

__global__ void k_scatter(const int* __restrict__ src, const int* __restrict__ dst, int E, int N,
                          int* __restrict__ cursor, int* __restrict__ col) {
    int t = blockIdx.x * blockDim.x + threadIdx.x;
    if (t < E) {
        int p = atomicAdd(&cursor[dst[t]], 1);
        col[p] = src[t];
    } else if (t < E + N) {
        int n = t - E;
        int p = atomicAdd(&cursor[n], 1);
        col[p] = n;
    }
}

// ---------------- fp32 tiled GEMM, epilogue scales row by dinv ----------------
// Y[row, col] = dinv[row] * sum_k A[row,k] * B[k,col]    (A: N x K, B: K x NB, Y: N x NB)
__global__ __launch_bounds__(256) void k_gemm_scale(const float* __restrict__ A, const float* __restrict__ B,
                                                    const float* __restrict__ dinv, float* __restrict__ Y,
                                                    int N, int K, int NB) {
    __shared__ float As[16][68];
    __shared__ float Bs[16][68];
    const int tid = threadIdx.x;
    const int row0 = blockIdx.x * 64;
    const int col0 = blockIdx.y * 64;
    const int tx = tid & 15, ty = tid >> 4;
    const int r = ty * 4, c = tx * 4;
    float acc[4][4] = {};
    const int lr = tid >> 2;          // A tile row 0..63
    const int lk = (tid & 3) * 4;     // A tile k 0,4,8,12
    const int bk = tid >> 4;          // B tile k 0..15
    const int bc = (tid & 15) * 4;    // B tile col
    const int arow = min(row0 + lr, N - 1);
    const float* aptr = A + (size_t)arow * K + lk;
    const float* bptr = B + (size_t)bk * NB + col0 + bc;
    for (int k0 = 0; k0 < K; k0 += 16) {
        float4 a4 = *(const float4*)(aptr + k0);
        float4 b4 = *(const float4*)(bptr + (size_t)k0 * NB);
        As[lk + 0][lr] = a4.x;
        As[lk + 1][lr] = a4.y;
        As[lk + 2][lr] = a4.z;
        As[lk + 3][lr] = a4.w;
        *(float4*)&Bs[bk][bc] = b4;
        __syncthreads();
#pragma unroll
        for (int kk = 0; kk < 16; ++kk) {
            float4 a = *(const float4*)&As[kk][r];
            float4 b = *(const float4*)&Bs[kk][c];
            acc[0][0] += a.x * b.x; acc[0][1] += a.x * b.y; acc[0][2] += a.x * b.z; acc[0][3] += a.x * b.w;
            acc[1][0] += a.y * b.x; acc[1][1] += a.y * b.y; acc[1][2] += a.y * b.z; acc[1][3] += a.y * b.w;
            acc[2][0] += a.z * b.x; acc[2][1] += a.z * b.y; acc[2][2] += a.z * b.z; acc[2][3] += a.z * b.w;
            acc[3][0] += a.w * b.x; acc[3][1] += a.w * b.y; acc[3][2] += a.w * b.z; acc[3][3] += a.w * b.w;
        }
        __syncthreads();
    }
#pragma unroll
    for (int i = 0; i < 4; ++i) {
        int rr = row0 + r + i;
        if (rr < N) {
            float s = dinv[rr];
            float4 v = make_float4(acc[i][0] * s, acc[i][1] * s, acc[i][2] * s, acc[i][3] * s);
            *(float4*)&Y[(size_t)rr * NB + col0 + c] = v;
        }
    }
}

// ---------------- final GEMM: A(N x K) @ [Bmu | Bls] (K x 2*Cout) + bias, writes [2, N, Cout] ----------------
__global__ __launch_bounds__(256) void k_gemm_out(const float* __restrict__ A, const float* __restrict__ Bmu,
                                                  const float* __restrict__ Bls, const float* __restrict__ bmu,
                                                  const float* __restrict__ bls, float* __restrict__ out,
                                                  int N, int K, int Cout) {
    __shared__ float As[16][68];
    __shared__ float Bs[16][68];
    const int tid = threadIdx.x;
    const int row0 = blockIdx.x * 64;
    const int col0 = blockIdx.y * 64;
    const int tx = tid & 15, ty = tid >> 4;
    const int r = ty * 4, c = tx * 4;
    float acc[4][4] = {};
    const int lr = tid >> 2;
    const int lk = (tid & 3) * 4;
    const int bk = tid >> 4;
    const int bc = (tid & 15) * 4;
    const int arow = min(row0 + lr, N - 1);
    const float* aptr = A + (size_t)arow * K + lk;
    const int cc = col0 + bc;
    const float* bsrc = (cc < Cout) ? (Bmu + cc) : (Bls + (cc - Cout));
    for (int k0 = 0; k0 < K; k0 += 16) {
        float4 a4 = *(const float4*)(aptr + k0);
        float4 b4 = *(const float4*)(bsrc + (size_t)(k0 + bk) * Cout);
        As[lk + 0][lr] = a4.x;
        As[lk + 1][lr] = a4.y;
        As[lk + 2][lr] = a4.z;
        As[lk + 3][lr] = a4.w;
        *(float4*)&Bs[bk][bc] = b4;
        __syncthreads();
#pragma unroll
        for (int kk = 0; kk < 16; ++kk) {
            float4 a = *(const float4*)&As[kk][r];
            float4 b = *(const float4*)&Bs[kk][c];
            acc[0][0] += a.x * b.x; acc[0][1] += a.x * b.y; acc[0][2] += a.x * b.z; acc[0][3] += a.x * b.w;
            acc[1][0] += a.y * b.x; acc[1][1] += a.y * b.y; acc[1][2] += a.y * b.z; acc[1][3] += a.y * b.w;
            acc[2][0] += a.z * b.x; acc[2][1] += a.z * b.y; acc[2][2] += a.z * b.z; acc[2][3] += a.z * b.w;
            acc[3][0] += a.w * b.x; acc[3][1] += a.w * b.y; acc[3][2] += a.w * b.z; acc[3][3] += a.w * b.w;
        }
        __syncthreads();
    }
    const int oc = col0 + c;
    const bool is_mu = (oc < Cout);
    const int ocl = is_mu ? oc : (oc - Cout);
    const float* bias = is_mu ? bmu : bls;
    float4 bv = *(const float4*)&bias[ocl];
    const size_t obase = is_mu ? 0 : (size_t)N * Cout;
#pragma unroll
    for (int i = 0; i < 4; ++i) {
        int rr = row0 + r + i;
        if (rr < N) {
            float4 v = make_float4(acc[i][0] + bv.x, acc[i][1] + bv.y, acc[i][2] + bv.z, acc[i][3] + bv.w);
            *(float4*)&out[obase + (size_t)rr * Cout + ocl] = v;
        }
    }
}

// ---------------- CSR aggregation: one wave per node, 256 cols as float4/lane ----------------
// relu_mode=1: Yout[n] = dinv[n] * relu(dinv[n]*sum + bias)   (pre-scales for next layer)
// relu_mode=0: Yout[n] = dinv[n] * sum
__global__ __launch_bounds__(256) void k_agg(const float* __restrict__ Yin, const int* __restrict__ row_ptr,
                                             const int* __restrict__ col, const float* __restrict__ dinv,
                                             const float* __restrict__ bias, float* __restrict__ Yout,
                                             int N, int relu_mode) {
    const int n = blockIdx.x * 4 + (threadIdx.x >> 6);
    if (n >= N) return;
    const int lane = threadIdx.x & 63;
    const int c = lane * 4;
    const int jb = row_ptr[n], je = row_ptr[n + 1];
    float ax = 0.f, ay = 0.f, az = 0.f, aw = 0.f;
    int j = jb;
    for (; j + 1 < je; j += 2) {
        int s0 = col[j], s1 = col[j + 1];
        float4 v0 = *(const float4*)&Yin[(size_t)s0 * 256 + c];
        float4 v1 = *(const float4*)&Yin[(size_t)s1 * 256 + c];
        ax += v0.x + v1.x; ay += v0.y + v1.y; az += v0.z + v1.z; aw += v0.w + v1.w;
    }
    if (j < je) {
        int s0 = col[j];
        float4 v0 = *(const float4*)&Yin[(size_t)s0 * 256 + c];
        ax += v0.x; ay += v0.y; az += v0.z; aw += v0.w;
    }
    const float dn = dinv[n];
    float4 o;
    if (relu_mode) {
        float4 b = *(const float4*)&bias[c];
        o.x = fmaxf(dn * ax + b.x, 0.f) * dn;
        o.y = fmaxf(dn * ay + b.y, 0.f) * dn;
        o.z = fmaxf(dn * az + b.z, 0.f) * dn;
        o.w = fmaxf(dn * aw + b.w, 0.f) * dn;
    } else {
        o = make_float4(dn * ax, dn * ay, dn * az, dn * aw);
    }
    *(float4*)&Yout[(size_t)n * 256 + c] = o;
}

// ---------------- launch ----------------

extern "C" void kernel_launch(void* const* d_in, const int* in_sizes, int n_in,
                              void* d_out, int out_size, void* d_ws, size_t ws_size,
                              hipStream_t stream) {
    const float* x   = (const float*)d_in[0];
    const int*   ei  = (const int*)d_in[1];
    const float* W1  = (const float*)d_in[2];
    const float* b1  = (const float*)d_in[3];
    const float* Wmu = (const float*)d_in[4];
    const float* bmu = (const float*)d_in[5];
    const float* Wls = (const float*)d_in[6];
    const float* bls = (const float*)d_in[7];

    const int H    = in_sizes[3];        // 256
    const int Cin  = in_sizes[2] / H;    // 512
    const int Cout = in_sizes[5];        // 128
    const int N    = in_sizes[0] / Cin;  // 50000
    const int E    = in_sizes[1] / 2;    // 800000
    const int* srcv = ei;
    const int* dstv = ei + E;

    char* w = (char*)d_ws;
    size_t off = 0;
    auto alloc = [&](size_t bytes) -> void* {
        void* p = w + off;
        off = (off + bytes + 255) & ~(size_t)255;
        return p;
    };
    int*   cnt     = (int*)alloc((size_t)N * 4);
    int*   cursor  = (int*)alloc((size_t)N * 4);
    int*   row_ptr = (int*)alloc((size_t)(N + 1) * 4);
    float* dinv    = (float*)alloc((size_t)N * 4);
    int*   col     = (int*)alloc((size_t)(E + N) * 4);
    float* y       = (float*)alloc((size_t)N * H * 4);
    float* y2      = (float*)alloc((size_t)N * H * 4);
    float* g       = y;  // y is dead after agg1; reuse for g
    (void)ws_size; (void)n_in; (void)out_size;

    k_init_cnt<<<ceil_div(N, 256), 256, 0, stream>>>(cnt, N);
    k_count<<<ceil_div(E, 256), 256, 0, stream>>>(dstv, E, cnt);
    k_scan<<<1, 256, 0, stream>>>(cnt, row_ptr, cursor, dinv, N);
    k_scatter<<<ceil_div(E + N, 256), 256, 0, stream>>>(srcv, dstv, E, N, cursor, col);

    dim3 g1(ceil_div(N, 64), H / 64);
    k_gemm_scale<<<g1, 256, 0, stream>>>(x, W1, dinv, y, N, Cin, H);

    k_agg<<<ceil_div(N, 4), 256, 0, stream>>>(y, row_ptr, col, dinv, b1, y2, N, 1);
    k_agg<<<ceil_div(N, 4), 256, 0, stream>>>(y2, row_ptr, col, dinv, nullptr, g, N, 0);

    dim3 g2(ceil_div(N, 64), (2 * Cout) / 64);
    k_gemm_out<<<g2, 256, 0, stream>>>(g, Wmu, Wls, bmu, bls, (float*)d_out, N, H, Cout);
}

// Round 2
// 597.660 us; speedup vs baseline: 1.5369x; 1.5369x over previous
//
#include <hip/hip_runtime.h>

static inline int ceil_div(int a, int b) { return (a + b - 1) / b; }

typedef __attribute__((ext_vector_type(8))) __bf16 bf16x8;
typedef __attribute__((ext_vector_type(8))) unsigned short ushort8;
typedef __attribute__((ext_vector_type(4))) float f32x4;

__device__ __forceinline__ unsigned short f2bf(float f) {
    union { float f; unsigned u; } v; v.f = f;
    unsigned r = v.u + 0x7fffu + ((v.u >> 16) & 1u);
    return (unsigned short)(r >> 16);
}
__device__ __forceinline__ float blo(unsigned u) {
    union { unsigned u; float f; } x; x.u = u << 16; return x.f;
}
__device__ __forceinline__ float bhi(unsigned u) {
    union { unsigned u; float f; } x; x.u = u & 0xffff0000u; return x.f;
}

// ---------------- graph preprocessing ----------------

__global__ void k_init_cnt(int* __restrict__ cnt, int N) {
    int i = blockIdx.x * blockDim.x + threadIdx.x;
    if (i < N) cnt[i] = 1;  // self-loop
}

__global__ void k_count(const int* __restrict__ dst, int E, int* __restrict__ cnt) {
    int e = blockIdx.x * blockDim.x + threadIdx.x;
    if (e < E) atomicAdd(&cnt[dst[e]], 1);
}

// single-block scan, coalesced: wave-stride loads + shuffle prefix
__global__ __launch_bounds__(256) void k_scan(const int* __restrict__ cnt, int* __restrict__ row_ptr,
                                              int* __restrict__ cursor, float* __restrict__ dinv, int N) {
    __shared__ int wsum[4];
    __shared__ int wbase[4];
    const int tid = threadIdx.x;
    const int wave = tid >> 6, lane = tid & 63;
    const int W0 = ((N + 255) / 256) * 64;  // elems per wave, multiple of 64
    const int b = wave * W0;
    const int e = min(b + W0, N);
    // phase 1: wave totals (coalesced stride-64)
    int s = 0;
    for (int i = b + lane; i < e; i += 64) s += cnt[i];
    for (int off = 32; off > 0; off >>= 1) s += __shfl_down(s, off);
    if (lane == 0) wsum[wave] = s;
    __syncthreads();
    if (tid == 0) {
        int r = 0;
        for (int i = 0; i < 4; ++i) { wbase[i] = r; r += wsum[i]; }
        row_ptr[N] = r;
    }
    __syncthreads();
    // phase 2: per-64-chunk inclusive scan via shuffles
    int run = wbase[wave];
    for (int i0 = b; i0 < e; i0 += 64) {
        int i = i0 + lane;
        int c = (i < e) ? cnt[i] : 0;
        int x = c;
        for (int off = 1; off < 64; off <<= 1) {
            int t = __shfl_up(x, off);
            if (lane >= off) x += t;
        }
        if (i < e) {
            int excl = run + x - c;
            row_ptr[i] = excl;
            cursor[i] = excl;
            dinv[i] = rsqrtf((float)c);
        }
        run += __shfl(x, 63);
    }
}

__global__ void k_scatter(const int* __restrict__ src, const int* __restrict__ dst, int E, int N,
                          int* __restrict__ cursor, int* __restrict__ col) {
    int t = blockIdx.x * blockDim.x + threadIdx.x;
    if (t < E) {
        int p = atomicAdd(&cursor[dst[t]], 1);
        col[p] = src[t];
    } else if (t < E + N) {
        int n = t - E;
        int p = atomicAdd(&cursor[n], 1);
        col[p] = n;
    }
}

// convert W1 [K1 x H] -> W1t bf16 [H x K1] (transposed), and Wmu/Wls [H x Cout] -> Wct bf16 [2Cout x H]
__global__ void k_prep_w(const float* __restrict__ W1, const float* __restrict__ Wmu,
                         const float* __restrict__ Wls, unsigned short* __restrict__ W1t,
                         unsigned short* __restrict__ Wct, int K1, int H, int Cout) {
    int t = blockIdx.x * blockDim.x + threadIdx.x;
    int n1 = H * K1;
    int n2 = 2 * Cout * H;
    if (t < n1) {
        int c = t / K1, k = t - c * K1;
        W1t[t] = f2bf(W1[(size_t)k * H + c]);
    } else if (t < n1 + n2) {
        int u = t - n1;
        int c = u / H, k = u - c * H;
        float v = (c < Cout) ? Wmu[(size_t)k * Cout + c] : Wls[(size_t)k * Cout + (c - Cout)];
        Wct[u] = f2bf(v);
    }
}

// ---------------- GEMM1: y[bf16] = bf16( dinv[row] * (x @ W1) ) ----------------
// x: N x K fp32 (K=512), W1t: 256 x K bf16 (row = out col), y: N x 256 bf16
__global__ __launch_bounds__(256) void k_gemm1(const float* __restrict__ x, const unsigned short* __restrict__ W1t,
                                               const float* __restrict__ dinv, unsigned short* __restrict__ y,
                                               int N, int K) {
    __shared__ __align__(16) unsigned short As[64][40];  // 64 rows x 32 k, stride 40 (80B, 16B-aligned)
    const int tid = threadIdx.x;
    const int wave = tid >> 6, lane = tid & 63;
    const int quad = lane >> 4, l16 = lane & 15;
    const int row0 = blockIdx.x * 64;
    const int n0 = wave * 64;  // wave owns 64 of the 256 output cols
    f32x4 acc[4][4] = {};
    // A staging: thread -> (row sr, 8-wide k chunk kc)
    const int sr = tid >> 2;
    const int kc = (tid & 3) * 8;
    const int arow = min(row0 + sr, N - 1);
    const float* ap = x + (size_t)arow * K + kc;
    const unsigned short* bp = W1t + (size_t)(n0 + l16) * K + quad * 8;

    for (int k0 = 0; k0 < K; k0 += 32) {
        float4 a0 = *(const float4*)(ap + k0);
        float4 a1 = *(const float4*)(ap + k0 + 4);
        ushort8 t;
        t[0] = f2bf(a0.x); t[1] = f2bf(a0.y); t[2] = f2bf(a0.z); t[3] = f2bf(a0.w);
        t[4] = f2bf(a1.x); t[5] = f2bf(a1.y); t[6] = f2bf(a1.z); t[7] = f2bf(a1.w);
        *(ushort8*)&As[sr][kc] = t;
        bf16x8 bfr[4];
#pragma unroll
        for (int j = 0; j < 4; ++j) bfr[j] = *(const bf16x8*)(bp + (size_t)j * 16 * K + k0);
        __syncthreads();
#pragma unroll
        for (int i = 0; i < 4; ++i) {
            bf16x8 afr = *(const bf16x8*)&As[i * 16 + l16][quad * 8];
#pragma unroll
            for (int j = 0; j < 4; ++j)
                acc[i][j] = __builtin_amdgcn_mfma_f32_16x16x32_bf16(afr, bfr[j], acc[i][j], 0, 0, 0);
        }
        __syncthreads();
    }
#pragma unroll
    for (int i = 0; i < 4; ++i) {
        const int gr = row0 + i * 16 + quad * 4;
#pragma unroll
        for (int r = 0; r < 4; ++r) {
            const int row = gr + r;
            if (row < N) {
                const float s = dinv[row];
#pragma unroll
                for (int j = 0; j < 4; ++j) {
                    const int gc = n0 + j * 16 + l16;
                    y[(size_t)row * 256 + gc] = f2bf(acc[i][j][r] * s);
                }
            }
        }
    }
}

// ---------------- GEMM2: out[2,N,Cout] = (g @ [Wmu|Wls]) + bias ----------------
// g: N x 256 bf16, Wct: 256 x 256 bf16 (row = out col in [mu|ls], cols = k), out fp32
__global__ __launch_bounds__(256) void k_gemm2(const unsigned short* __restrict__ g,
                                               const unsigned short* __restrict__ Wct,
                                               const float* __restrict__ bmu, const float* __restrict__ bls,
                                               float* __restrict__ out, int N, int Cout) {
    __shared__ __align__(16) unsigned short As[64][40];
    const int K = 256;
    const int tid = threadIdx.x;
    const int wave = tid >> 6, lane = tid & 63;
    const int quad = lane >> 4, l16 = lane & 15;
    const int row0 = blockIdx.x * 64;
    const int n0 = wave * 64;
    f32x4 acc[4][4] = {};
    const int sr = tid >> 2;
    const int kc = (tid & 3) * 8;
    const int arow = min(row0 + sr, N - 1);
    const unsigned short* ap = g + (size_t)arow * K + kc;
    const unsigned short* bp = Wct + (size_t)(n0 + l16) * K + quad * 8;

    for (int k0 = 0; k0 < K; k0 += 32) {
        ushort8 t = *(const ushort8*)(ap + k0);
        *(ushort8*)&As[sr][kc] = t;
        bf16x8 bfr[4];
#pragma unroll
        for (int j = 0; j < 4; ++j) bfr[j] = *(const bf16x8*)(bp + (size_t)j * 16 * K + k0);
        __syncthreads();
#pragma unroll
        for (int i = 0; i < 4; ++i) {
            bf16x8 afr = *(const bf16x8*)&As[i * 16 + l16][quad * 8];
#pragma unroll
            for (int j = 0; j < 4; ++j)
                acc[i][j] = __builtin_amdgcn_mfma_f32_16x16x32_bf16(afr, bfr[j], acc[i][j], 0, 0, 0);
        }
        __syncthreads();
    }
#pragma unroll
    for (int j = 0; j < 4; ++j) {
        const int c = n0 + j * 16 + l16;
        const bool is_mu = (c < Cout);
        const int ocl = is_mu ? c : (c - Cout);
        const float bv = is_mu ? bmu[ocl] : bls[ocl];
        const size_t obase = is_mu ? 0 : (size_t)N * Cout;
#pragma unroll
        for (int i = 0; i < 4; ++i) {
            const int gr = row0 + i * 16 + quad * 4;
#pragma unroll
            for (int r = 0; r < 4; ++r) {
                const int row = gr + r;
                if (row < N) out[obase + (size_t)row * Cout + ocl] = acc[i][j][r] + bv;
            }
        }
    }
}

// ---------------- CSR aggregation on bf16 rows (256 cols) ----------------
// relu_mode=1: Yout[n] = bf16( dinv[n] * relu(dinv[n]*sum + bias) )
// relu_mode=0: Yout[n] = bf16( dinv[n] * sum )
__global__ __launch_bounds__(256) void k_agg(const unsigned short* __restrict__ Yin,
                                             const int* __restrict__ row_ptr, const int* __restrict__ col,
                                             const float* __restrict__ dinv, const float* __restrict__ bias,
                                             unsigned short* __restrict__ Yout, int N, int relu_mode) {
    const int n = blockIdx.x * 4 + (threadIdx.x >> 6);
    if (n >= N) return;
    const int lane = threadIdx.x & 63;
    const int c = lane * 4;
    const int jb = row_ptr[n], je = row_ptr[n + 1];
    float ax = 0.f, ay = 0.f, az = 0.f, aw = 0.f;
    int j = jb;
    for (; j + 1 < je; j += 2) {
        const int s0 = col[j], s1 = col[j + 1];
        const uint2 v0 = *(const uint2*)(Yin + (size_t)s0 * 256 + c);
        const uint2 v1 = *(const uint2*)(Yin + (size_t)s1 * 256 + c);
        ax += blo(v0.x) + blo(v1.x); ay += bhi(v0.x) + bhi(v1.x);
        az += blo(v0.y) + blo(v1.y); aw += bhi(v0.y) + bhi(v1.y);
    }
    if (j < je) {
        const int s0 = col[j];
        const uint2 v0 = *(const uint2*)(Yin + (size_t)s0 * 256 + c);
        ax += blo(v0.x); ay += bhi(v0.x); az += blo(v0.y); aw += bhi(v0.y);
    }
    const float dn = dinv[n];
    float ox, oy, oz, ow;
    if (relu_mode) {
        const float4 b = *(const float4*)&bias[c];
        ox = fmaxf(dn * ax + b.x, 0.f) * dn;
        oy = fmaxf(dn * ay + b.y, 0.f) * dn;
        oz = fmaxf(dn * az + b.z, 0.f) * dn;
        ow = fmaxf(dn * aw + b.w, 0.f) * dn;
    } else {
        ox = dn * ax; oy = dn * ay; oz = dn * az; ow = dn * aw;
    }
    uint2 o;
    o.x = (unsigned)f2bf(ox) | ((unsigned)f2bf(oy) << 16);
    o.y = (unsigned)f2bf(oz) | ((unsigned)f2bf(ow) << 16);
    *(uint2*)(Yout + (size_t)n * 256 + c) = o;
}

// ---------------- launch ----------------

extern "C" void kernel_launch(void* const* d_in, const int* in_sizes, int n_in,
                              void* d_out, int out_size, void* d_ws, size_t ws_size,
                              hipStream_t stream) {
    const float* x   = (const float*)d_in[0];
    const int*   ei  = (const int*)d_in[1];
    const float* W1  = (const float*)d_in[2];
    const float* b1  = (const float*)d_in[3];
    const float* Wmu = (const float*)d_in[4];
    const float* bmu = (const float*)d_in[5];
    const float* Wls = (const float*)d_in[6];
    const float* bls = (const float*)d_in[7];

    const int H    = in_sizes[3];        // 256
    const int Cin  = in_sizes[2] / H;    // 512
    const int Cout = in_sizes[5];        // 128
    const int N    = in_sizes[0] / Cin;  // 50000
    const int E    = in_sizes[1] / 2;    // 800000
    const int* srcv = ei;
    const int* dstv = ei + E;

    char* w = (char*)d_ws;
    size_t off = 0;
    auto alloc = [&](size_t bytes) -> void* {
        void* p = w + off;
        off = (off + bytes + 255) & ~(size_t)255;
        return p;
    };
    int*            cnt     = (int*)alloc((size_t)N * 4);
    int*            cursor  = (int*)alloc((size_t)N * 4);
    int*            row_ptr = (int*)alloc((size_t)(N + 1) * 4);
    float*          dinv    = (float*)alloc((size_t)N * 4);
    int*            col     = (int*)alloc((size_t)(E + N) * 4);
    unsigned short* W1t     = (unsigned short*)alloc((size_t)H * Cin * 2);
    unsigned short* Wct     = (unsigned short*)alloc((size_t)2 * Cout * H * 2);
    unsigned short* y       = (unsigned short*)alloc((size_t)N * H * 2);
    unsigned short* y2      = (unsigned short*)alloc((size_t)N * H * 2);
    unsigned short* g       = y;  // y dead after agg1; reuse
    (void)ws_size; (void)n_in; (void)out_size;

    k_init_cnt<<<ceil_div(N, 256), 256, 0, stream>>>(cnt, N);
    k_count<<<ceil_div(E, 256), 256, 0, stream>>>(dstv, E, cnt);
    k_scan<<<1, 256, 0, stream>>>(cnt, row_ptr, cursor, dinv, N);
    k_scatter<<<ceil_div(E + N, 256), 256, 0, stream>>>(srcv, dstv, E, N, cursor, col);
    k_prep_w<<<ceil_div(H * Cin + 2 * Cout * H, 256), 256, 0, stream>>>(W1, Wmu, Wls, W1t, Wct, Cin, H, Cout);

    k_gemm1<<<ceil_div(N, 64), 256, 0, stream>>>(x, W1t, dinv, y, N, Cin);

    k_agg<<<ceil_div(N, 4), 256, 0, stream>>>(y, row_ptr, col, dinv, b1, y2, N, 1);
    k_agg<<<ceil_div(N, 4), 256, 0, stream>>>(y2, row_ptr, col, dinv, nullptr, g, N, 0);

    k_gemm2<<<ceil_div(N, 64), 256, 0, stream>>>(g, Wct, bmu, bls, (float*)d_out, N, Cout);
}

// Round 3
// 462.316 us; speedup vs baseline: 1.9868x; 1.2928x over previous
//
#include <hip/hip_runtime.h>

static inline int ceil_div(int a, int b) { return (a + b - 1) / b; }

typedef __attribute__((ext_vector_type(8))) __bf16 bf16x8;
typedef __attribute__((ext_vector_type(8))) unsigned short ushort8;
typedef __attribute__((ext_vector_type(4))) float f32x4;

__device__ __forceinline__ unsigned short f2bf(float f) {
    union { float f; unsigned u; } v; v.f = f;
    unsigned r = v.u + 0x7fffu + ((v.u >> 16) & 1u);
    return (unsigned short)(r >> 16);
}
__device__ __forceinline__ float blo(unsigned u) {
    union { unsigned u; float f; } x; x.u = u << 16; return x.f;
}
__device__ __forceinline__ float bhi(unsigned u) {
    union { unsigned u; float f; } x; x.u = u & 0xffff0000u; return x.f;
}

// ---------------- graph preprocessing ----------------

__global__ void k_init_cnt(int* __restrict__ cnt, int N) {
    int i = blockIdx.x * blockDim.x + threadIdx.x;
    if (i < N) cnt[i] = 1;  // self-loop
}

__global__ void k_count(const int* __restrict__ dst, int E, int* __restrict__ cnt) {
    int e = blockIdx.x * blockDim.x + threadIdx.x;
    if (e < E) atomicAdd(&cnt[dst[e]], 1);
}

// ---- hierarchical exclusive scan of cnt (N elems, 256/block) ----
// stage A: per-block sums
__global__ __launch_bounds__(256) void k_bsum(const int* __restrict__ cnt, int* __restrict__ bsum, int N) {
    __shared__ int ws[4];
    const int i = blockIdx.x * 256 + threadIdx.x;
    const int lane = threadIdx.x & 63, wave = threadIdx.x >> 6;
    int v = (i < N) ? cnt[i] : 0;
    for (int off = 32; off > 0; off >>= 1) v += __shfl_down(v, off);
    if (lane == 0) ws[wave] = v;
    __syncthreads();
    if (threadIdx.x == 0) bsum[blockIdx.x] = ws[0] + ws[1] + ws[2] + ws[3];
}

// stage B: single small block scans the block sums (nb <= 256)
__global__ __launch_bounds__(256) void k_scan_bsum(const int* __restrict__ bsum, int* __restrict__ bbase,
                                                   int nb, int* __restrict__ row_ptr, int N) {
    __shared__ int ws[4];
    const int tid = threadIdx.x;
    const int lane = tid & 63, wave = tid >> 6;
    const int v = (tid < nb) ? bsum[tid] : 0;
    int x = v;
    for (int off = 1; off < 64; off <<= 1) {
        int t = __shfl_up(x, off);
        if (lane >= off) x += t;
    }
    if (lane == 63) ws[wave] = x;
    __syncthreads();
    if (tid == 0) {
        int r = 0;
        for (int i = 0; i < 4; ++i) { int t = ws[i]; ws[i] = r; r += t; }
        row_ptr[N] = r;
    }
    __syncthreads();
    if (tid < nb) bbase[tid] = ws[wave] + x - v;
}

// stage C: per-block local scan + apply base; writes row_ptr, cursor, dinv
__global__ __launch_bounds__(256) void k_scan_apply(const int* __restrict__ cnt, const int* __restrict__ bbase,
                                                    int* __restrict__ row_ptr, int* __restrict__ cursor,
                                                    float* __restrict__ dinv, int N) {
    __shared__ int ws[4];
    const int i = blockIdx.x * 256 + threadIdx.x;
    const int lane = threadIdx.x & 63, wave = threadIdx.x >> 6;
    const int c = (i < N) ? cnt[i] : 0;
    int x = c;
    for (int off = 1; off < 64; off <<= 1) {
        int t = __shfl_up(x, off);
        if (lane >= off) x += t;
    }
    if (lane == 63) ws[wave] = x;
    __syncthreads();
    if (threadIdx.x == 0) {
        int r = 0;
        for (int k = 0; k < 4; ++k) { int t = ws[k]; ws[k] = r; r += t; }
    }
    __syncthreads();
    if (i < N) {
        const int excl = bbase[blockIdx.x] + ws[wave] + x - c;
        row_ptr[i] = excl;
        cursor[i] = excl;
        dinv[i] = rsqrtf((float)c);
    }
}

__global__ void k_scatter(const int* __restrict__ src, const int* __restrict__ dst, int E, int N,
                          int* __restrict__ cursor, int* __restrict__ col) {
    int t = blockIdx.x * blockDim.x + threadIdx.x;
    if (t < E) {
        int p = atomicAdd(&cursor[dst[t]], 1);
        col[p] = src[t];
    } else if (t < E + N) {
        int n = t - E;
        int p = atomicAdd(&cursor[n], 1);
        col[p] = n;
    }
}

// convert W1 [K1 x H] -> W1t bf16 [H x K1] (transposed), and Wmu/Wls [H x Cout] -> Wct bf16 [2Cout x H]
__global__ void k_prep_w(const float* __restrict__ W1, const float* __restrict__ Wmu,
                         const float* __restrict__ Wls, unsigned short* __restrict__ W1t,
                         unsigned short* __restrict__ Wct, int K1, int H, int Cout) {
    int t = blockIdx.x * blockDim.x + threadIdx.x;
    int n1 = H * K1;
    int n2 = 2 * Cout * H;
    if (t < n1) {
        int c = t / K1, k = t - c * K1;
        W1t[t] = f2bf(W1[(size_t)k * H + c]);
    } else if (t < n1 + n2) {
        int u = t - n1;
        int c = u / H, k = u - c * H;
        float v = (c < Cout) ? Wmu[(size_t)k * Cout + c] : Wls[(size_t)k * Cout + (c - Cout)];
        Wct[u] = f2bf(v);
    }
}

// ---------------- GEMM1: y[bf16] = bf16( dinv[row] * (x @ W1) ) ----------------
__global__ __launch_bounds__(256) void k_gemm1(const float* __restrict__ x, const unsigned short* __restrict__ W1t,
                                               const float* __restrict__ dinv, unsigned short* __restrict__ y,
                                               int N, int K) {
    __shared__ __align__(16) unsigned short As[64][40];
    const int tid = threadIdx.x;
    const int wave = tid >> 6, lane = tid & 63;
    const int quad = lane >> 4, l16 = lane & 15;
    const int row0 = blockIdx.x * 64;
    const int n0 = wave * 64;
    f32x4 acc[4][4] = {};
    const int sr = tid >> 2;
    const int kc = (tid & 3) * 8;
    const int arow = min(row0 + sr, N - 1);
    const float* ap = x + (size_t)arow * K + kc;
    const unsigned short* bp = W1t + (size_t)(n0 + l16) * K + quad * 8;

    for (int k0 = 0; k0 < K; k0 += 32) {
        float4 a0 = *(const float4*)(ap + k0);
        float4 a1 = *(const float4*)(ap + k0 + 4);
        ushort8 t;
        t[0] = f2bf(a0.x); t[1] = f2bf(a0.y); t[2] = f2bf(a0.z); t[3] = f2bf(a0.w);
        t[4] = f2bf(a1.x); t[5] = f2bf(a1.y); t[6] = f2bf(a1.z); t[7] = f2bf(a1.w);
        *(ushort8*)&As[sr][kc] = t;
        bf16x8 bfr[4];
#pragma unroll
        for (int j = 0; j < 4; ++j) bfr[j] = *(const bf16x8*)(bp + (size_t)j * 16 * K + k0);
        __syncthreads();
#pragma unroll
        for (int i = 0; i < 4; ++i) {
            bf16x8 afr = *(const bf16x8*)&As[i * 16 + l16][quad * 8];
#pragma unroll
            for (int j = 0; j < 4; ++j)
                acc[i][j] = __builtin_amdgcn_mfma_f32_16x16x32_bf16(afr, bfr[j], acc[i][j], 0, 0, 0);
        }
        __syncthreads();
    }
#pragma unroll
    for (int i = 0; i < 4; ++i) {
        const int gr = row0 + i * 16 + quad * 4;
#pragma unroll
        for (int r = 0; r < 4; ++r) {
            const int row = gr + r;
            if (row < N) {
                const float s = dinv[row];
#pragma unroll
                for (int j = 0; j < 4; ++j) {
                    const int gc = n0 + j * 16 + l16;
                    y[(size_t)row * 256 + gc] = f2bf(acc[i][j][r] * s);
                }
            }
        }
    }
}

// ---------------- GEMM2: out[2,N,Cout] = (g @ [Wmu|Wls]) + bias ----------------
__global__ __launch_bounds__(256) void k_gemm2(const unsigned short* __restrict__ g,
                                               const unsigned short* __restrict__ Wct,
                                               const float* __restrict__ bmu, const float* __restrict__ bls,
                                               float* __restrict__ out, int N, int Cout) {
    __shared__ __align__(16) unsigned short As[64][40];
    const int K = 256;
    const int tid = threadIdx.x;
    const int wave = tid >> 6, lane = tid & 63;
    const int quad = lane >> 4, l16 = lane & 15;
    const int row0 = blockIdx.x * 64;
    const int n0 = wave * 64;
    f32x4 acc[4][4] = {};
    const int sr = tid >> 2;
    const int kc = (tid & 3) * 8;
    const int arow = min(row0 + sr, N - 1);
    const unsigned short* ap = g + (size_t)arow * K + kc;
    const unsigned short* bp = Wct + (size_t)(n0 + l16) * K + quad * 8;

    for (int k0 = 0; k0 < K; k0 += 32) {
        ushort8 t = *(const ushort8*)(ap + k0);
        *(ushort8*)&As[sr][kc] = t;
        bf16x8 bfr[4];
#pragma unroll
        for (int j = 0; j < 4; ++j) bfr[j] = *(const bf16x8*)(bp + (size_t)j * 16 * K + k0);
        __syncthreads();
#pragma unroll
        for (int i = 0; i < 4; ++i) {
            bf16x8 afr = *(const bf16x8*)&As[i * 16 + l16][quad * 8];
#pragma unroll
            for (int j = 0; j < 4; ++j)
                acc[i][j] = __builtin_amdgcn_mfma_f32_16x16x32_bf16(afr, bfr[j], acc[i][j], 0, 0, 0);
        }
        __syncthreads();
    }
#pragma unroll
    for (int j = 0; j < 4; ++j) {
        const int c = n0 + j * 16 + l16;
        const bool is_mu = (c < Cout);
        const int ocl = is_mu ? c : (c - Cout);
        const float bv = is_mu ? bmu[ocl] : bls[ocl];
        const size_t obase = is_mu ? 0 : (size_t)N * Cout;
#pragma unroll
        for (int i = 0; i < 4; ++i) {
            const int gr = row0 + i * 16 + quad * 4;
#pragma unroll
            for (int r = 0; r < 4; ++r) {
                const int row = gr + r;
                if (row < N) out[obase + (size_t)row * Cout + ocl] = acc[i][j][r] + bv;
            }
        }
    }
}

// ---------------- CSR aggregation on bf16 rows (256 cols), unroll-4 ----------------
__global__ __launch_bounds__(256) void k_agg(const unsigned short* __restrict__ Yin,
                                             const int* __restrict__ row_ptr, const int* __restrict__ col,
                                             const float* __restrict__ dinv, const float* __restrict__ bias,
                                             unsigned short* __restrict__ Yout, int N, int relu_mode) {
    const int n = blockIdx.x * 4 + (threadIdx.x >> 6);
    if (n >= N) return;
    const int lane = threadIdx.x & 63;
    const int c = lane * 4;
    const int jb = row_ptr[n], je = row_ptr[n + 1];
    float ax0 = 0.f, ay0 = 0.f, az0 = 0.f, aw0 = 0.f;
    float ax1 = 0.f, ay1 = 0.f, az1 = 0.f, aw1 = 0.f;
    int j = jb;
    for (; j + 3 < je; j += 4) {
        const int s0 = col[j], s1 = col[j + 1], s2 = col[j + 2], s3 = col[j + 3];
        const uint2 v0 = *(const uint2*)(Yin + (size_t)s0 * 256 + c);
        const uint2 v1 = *(const uint2*)(Yin + (size_t)s1 * 256 + c);
        const uint2 v2 = *(const uint2*)(Yin + (size_t)s2 * 256 + c);
        const uint2 v3 = *(const uint2*)(Yin + (size_t)s3 * 256 + c);
        ax0 += blo(v0.x) + blo(v1.x); ay0 += bhi(v0.x) + bhi(v1.x);
        az0 += blo(v0.y) + blo(v1.y); aw0 += bhi(v0.y) + bhi(v1.y);
        ax1 += blo(v2.x) + blo(v3.x); ay1 += bhi(v2.x) + bhi(v3.x);
        az1 += blo(v2.y) + blo(v3.y); aw1 += bhi(v2.y) + bhi(v3.y);
    }
    for (; j < je; ++j) {
        const int s0 = col[j];
        const uint2 v0 = *(const uint2*)(Yin + (size_t)s0 * 256 + c);
        ax0 += blo(v0.x); ay0 += bhi(v0.x); az0 += blo(v0.y); aw0 += bhi(v0.y);
    }
    const float ax = ax0 + ax1, ay = ay0 + ay1, az = az0 + az1, aw = aw0 + aw1;
    const float dn = dinv[n];
    float ox, oy, oz, ow;
    if (relu_mode) {
        const float4 b = *(const float4*)&bias[c];
        ox = fmaxf(dn * ax + b.x, 0.f) * dn;
        oy = fmaxf(dn * ay + b.y, 0.f) * dn;
        oz = fmaxf(dn * az + b.z, 0.f) * dn;
        ow = fmaxf(dn * aw + b.w, 0.f) * dn;
    } else {
        ox = dn * ax; oy = dn * ay; oz = dn * az; ow = dn * aw;
    }
    uint2 o;
    o.x = (unsigned)f2bf(ox) | ((unsigned)f2bf(oy) << 16);
    o.y = (unsigned)f2bf(oz) | ((unsigned)f2bf(ow) << 16);
    *(uint2*)(Yout + (size_t)n * 256 + c) = o;
}

// ---------------- launch ----------------

extern "C" void kernel_launch(void* const* d_in, const int* in_sizes, int n_in,
                              void* d_out, int out_size, void* d_ws, size_t ws_size,
                              hipStream_t stream) {
    const float* x   = (const float*)d_in[0];
    const int*   ei  = (const int*)d_in[1];
    const float* W1  = (const float*)d_in[2];
    const float* b1  = (const float*)d_in[3];
    const float* Wmu = (const float*)d_in[4];
    const float* bmu = (const float*)d_in[5];
    const float* Wls = (const float*)d_in[6];
    const float* bls = (const float*)d_in[7];

    const int H    = in_sizes[3];        // 256
    const int Cin  = in_sizes[2] / H;    // 512
    const int Cout = in_sizes[5];        // 128
    const int N    = in_sizes[0] / Cin;  // 50000
    const int E    = in_sizes[1] / 2;    // 800000
    const int* srcv = ei;
    const int* dstv = ei + E;

    char* w = (char*)d_ws;
    size_t off = 0;
    auto alloc = [&](size_t bytes) -> void* {
        void* p = w + off;
        off = (off + bytes + 255) & ~(size_t)255;
        return p;
    };
    const int nb = ceil_div(N, 256);
    int*            cnt     = (int*)alloc((size_t)N * 4);
    int*            cursor  = (int*)alloc((size_t)N * 4);
    int*            row_ptr = (int*)alloc((size_t)(N + 1) * 4);
    float*          dinv    = (float*)alloc((size_t)N * 4);
    int*            bsum    = (int*)alloc((size_t)nb * 4);
    int*            bbase   = (int*)alloc((size_t)nb * 4);
    int*            col     = (int*)alloc((size_t)(E + N) * 4);
    unsigned short* W1t     = (unsigned short*)alloc((size_t)H * Cin * 2);
    unsigned short* Wct     = (unsigned short*)alloc((size_t)2 * Cout * H * 2);
    unsigned short* y       = (unsigned short*)alloc((size_t)N * H * 2);
    unsigned short* y2      = (unsigned short*)alloc((size_t)N * H * 2);
    unsigned short* g       = y;  // y dead after agg1; reuse
    (void)ws_size; (void)n_in; (void)out_size;

    k_init_cnt<<<ceil_div(N, 256), 256, 0, stream>>>(cnt, N);
    k_count<<<ceil_div(E, 256), 256, 0, stream>>>(dstv, E, cnt);
    k_bsum<<<nb, 256, 0, stream>>>(cnt, bsum, N);
    k_scan_bsum<<<1, 256, 0, stream>>>(bsum, bbase, nb, row_ptr, N);
    k_scan_apply<<<nb, 256, 0, stream>>>(cnt, bbase, row_ptr, cursor, dinv, N);
    k_scatter<<<ceil_div(E + N, 256), 256, 0, stream>>>(srcv, dstv, E, N, cursor, col);
    k_prep_w<<<ceil_div(H * Cin + 2 * Cout * H, 256), 256, 0, stream>>>(W1, Wmu, Wls, W1t, Wct, Cin, H, Cout);

    k_gemm1<<<ceil_div(N, 64), 256, 0, stream>>>(x, W1t, dinv, y, N, Cin);

    k_agg<<<ceil_div(N, 4), 256, 0, stream>>>(y, row_ptr, col, dinv, b1, y2, N, 1);
    k_agg<<<ceil_div(N, 4), 256, 0, stream>>>(y2, row_ptr, col, dinv, nullptr, g, N, 0);

    k_gemm2<<<ceil_div(N, 64), 256, 0, stream>>>(g, Wct, bmu, bls, (float*)d_out, N, Cout);
}